// Round 7
// baseline (315.482 us; speedup 1.0000x reference)
//
#include <hip/hip_runtime.h>
#include <hip/hip_bf16.h>

#define NN 126   // nodes
#define TT 24    // seq len
#define FF 17    // input feat
#define HH 100   // hidden

// ---------- MFMA fragment geometry (identical to R5/R6) ----------
//  L0, kt 0..3  (K=128): k<17 x | k==17 bias | k=18+j h1 | pad 118..127
//  L1, kt 4..10 (K=224): k==0 ones(bias) | pad 1..3 | k=4+j h1 | k=104+j h2 | pad
#define NKT 11
#define NMT 25
#define PER_NODE (NKT * NMT * 512)                  // 140,800 bf16 per node
#define WFRAG_ELEMS ((size_t)NN * PER_NODE)         // 17,740,800
#define XFRAG_ELEMS ((size_t)NN * TT * 4 * 64 * 8)  // 6,193,152
#define WS_NEEDED ((WFRAG_ELEMS + XFRAG_ELEMS) * 2) // 47,867,904 B

typedef __attribute__((ext_vector_type(8))) short short8v;
typedef __attribute__((ext_vector_type(4))) float float4v;

__device__ __forceinline__ short f2bf(float f) {
    union { float f; unsigned u; } v; v.f = f;
    unsigned r = v.u + 0x7FFFu + ((v.u >> 16) & 1u);   // RNE
    return (short)(r >> 16);
}
#define LOG2E 1.4426950408889634f
__device__ __forceinline__ float sigm_(float x) {
    return __builtin_amdgcn_rcpf(1.0f + __builtin_amdgcn_exp2f(-LOG2E * x));
}
__device__ __forceinline__ float tanh_(float x) {
    return 1.0f - 2.0f * __builtin_amdgcn_rcpf(1.0f + __builtin_amdgcn_exp2f((2.0f * LOG2E) * x));
}
// exact versions for the fallback kernel
__device__ __forceinline__ float sigmf(float x) { return 1.0f / (1.0f + __expf(-x)); }
__device__ __forceinline__ float tanhf_(float x) { return 2.0f / (1.0f + __expf(-2.0f * x)) - 1.0f; }

// ---------------- merged prep: weights + x -> bf16 MFMA fragments ----------------
#define PW_THREADS (NN * NKT * NMT * 64)            // 2,217,600
#define PX_THREADS (NN * TT * 4 * 64)               // 774,144
#define PW_BLOCKS ((PW_THREADS + 255) / 256)        // 8664
#define PX_BLOCKS ((PX_THREADS + 255) / 256)        // 3024

__global__ void prep_all(const float* __restrict__ Wih0, const float* __restrict__ Whh0,
                         const float* __restrict__ bih0, const float* __restrict__ bhh0,
                         const float* __restrict__ Wih1, const float* __restrict__ Whh1,
                         const float* __restrict__ bih1, const float* __restrict__ bhh1,
                         const float* __restrict__ x,
                         short* __restrict__ wfrag, short* __restrict__ xfrag)
{
    if (blockIdx.x < PW_BLOCKS) {
        const int idx = blockIdx.x * 256 + threadIdx.x;
        if (idx >= PW_THREADS) return;
        const int lane = idx & 63;
        int r = idx >> 6;
        const int mt = r % NMT; r /= NMT;
        const int kt = r % NKT;
        const int n  = r / NKT;

        const int row16 = lane & 15, kq = lane >> 4;
        const int gr = mt * 16 + row16;
        const int cell = gr >> 2, g = gr & 3;
        const int orow = n * 400 + g * HH + cell;   // gate blocks i,f,g,o

        short8v pv;
        #pragma unroll
        for (int e = 0; e < 8; ++e) {
            const int kk = kq * 8 + e;
            float f = 0.0f;
            if (kt < 4) {                           // L0 packed
                const int k = kt * 32 + kk;
                if (k < FF)        f = Wih0[(size_t)orow * FF + k];
                else if (k == FF)  f = bih0[orow] + bhh0[orow];
                else { const int j = k - 18; if (j < HH) f = Whh0[(size_t)orow * HH + j]; }
            } else {                                // L1
                const int k = (kt - 4) * 32 + kk;
                if (k == 0)                       f = bih1[orow] + bhh1[orow];
                else if (k >= 4 && k < 4 + HH)    f = Wih1[(size_t)orow * HH + (k - 4)];
                else if (k >= 104 && k < 104+HH)  f = Whh1[(size_t)orow * HH + (k - 104)];
            }
            pv[e] = f2bf(f);
        }
        *(short8v*)(wfrag + (size_t)idx * 8) = pv;
    } else {
        const int idx = (blockIdx.x - PW_BLOCKS) * 256 + threadIdx.x;
        if (idx >= PX_THREADS) return;
        const int lane = idx & 63;
        int r = idx >> 6;
        const int bq = r & 3; r >>= 2;
        const int t = r % TT;
        const int n = r / TT;
        const int b = bq * 16 + (lane & 15);
        const int kq = lane >> 4;

        short8v pv;
        #pragma unroll
        for (int e = 0; e < 8; ++e) {
            const int k = kq * 8 + e;
            float f = 0.0f;
            if (k < FF)       f = x[(((size_t)b * TT + t) * NN + n) * FF + k];
            else if (k == FF) f = 1.0f;
            pv[e] = f2bf(pv[e]), pv[e] = f2bf(f);
        }
        *(short8v*)(xfrag + (size_t)idx * 8) = pv;
    }
}

// ---------------- main: 8-wave, batch-16/WG, weights-in-registers MFMA LSTM ----------------
// LDS (shorts): X0[4][64][8]=2048 | X1[7][64][8]=3584 | A24[11][64][8]=5632 = 11264 shorts (22.5 KB)
#define SX1 2048
#define SA24 (2048 + 3584)
#define LDS_SHORTS (SA24 + 11 * 64 * 8)

__global__ __launch_bounds__(512, 4)
void lstm_mfma6(const short* __restrict__ wfrag, const short* __restrict__ xfrag,
                const float* __restrict__ wlin, const float* __restrict__ blin,
                const float* __restrict__ wend, const float* __restrict__ bend,
                float* __restrict__ out)
{
    __shared__ short lds_s[LDS_SHORTS];
    short* X0  = lds_s;            // [kt 0..3][lane][e]
    short* X1  = lds_s + SX1;      // [kt 0..6][lane][e]
    short* A24 = lds_s + SA24;     // [kt 0..10][lane][e]  (tile 24, wave-7 only)
    float* red = (float*)lds_s;    // overlay, epilogue only

    const int n   = blockIdx.x >> 2;
    const int bq  = blockIdx.x & 3;           // batch quarter (16 each)
    const int tid = threadIdx.x, lane = tid & 63, w = tid >> 6;   // 8 waves
    const int cl  = lane & 15, q = lane >> 4;
    const int mt0 = w * 3;                    // waves 0..7: tiles mt0..mt0+2; wave 7 also tile 24
    const bool w7 = (w == 7);

    const short* wnode = wfrag + (size_t)n * PER_NODE;

    // ---- init: zero X frags; stage tile-24 A to LDS; weight tiles -> regs ----
    {
        const short8v z = {0,0,0,0,0,0,0,0};
        for (int i = tid; i < (4 + 7) * 64; i += 512)
            *(short8v*)(X0 + (size_t)i * 8) = z;
    }
    for (int i = tid; i < 11 * 64; i += 512) {
        const int kt = i >> 6, l = i & 63;
        *(short8v*)(A24 + (size_t)i * 8) =
            *(const short8v*)(wnode + (((size_t)kt * NMT + 24) * 64 + l) * 8);
    }
    short8v wr0[3][4], wr1[3][7];
    #pragma unroll
    for (int mi = 0; mi < 3; ++mi) {
        #pragma unroll
        for (int kt = 0; kt < 4; ++kt)
            wr0[mi][kt] = *(const short8v*)(
                wnode + (((size_t)kt * NMT + (mt0 + mi)) * 64 + lane) * 8);
        #pragma unroll
        for (int kt = 0; kt < 7; ++kt)
            wr1[mi][kt] = *(const short8v*)(
                wnode + (((size_t)(4 + kt) * NMT + (mt0 + mi)) * 64 + lane) * 8);
    }
    __syncthreads();
    // ones column for L1 bias (k=0 -> kt0, kq=0, e=0, cols 0..15)
    if (tid < 16) X1[(size_t)tid * 8 + 0] = (short)0x3F80;

    // x staging writes ONLY k=0..17 of X0 kt0 (k>=18 holds packed h1); wave 0 only
    auto stage_x = [&](int t) {
        if (t < TT && w == 0) {
            const short8v v = *(const short8v*)(
                xfrag + ((((size_t)n * TT + t) * 4 + bq) * 64 + lane) * 8);
            if (q < 2)       *(short8v*)(X0 + (size_t)lane * 8) = v;           // k 0..15
            else if (q == 2) *(int*)(X0 + (size_t)lane * 8) = *(const int*)&v; // k 16,17
        }
    };
    stage_x(0);
    __syncthreads();

    float c1[4], c2[4], macc[4];
    #pragma unroll
    for (int mi = 0; mi < 4; ++mi) { c1[mi] = 0.f; c2[mi] = 0.f; macc[mi] = 0.f; }

    const int b = bq * 16 + cl;   // this lane's global batch

    for (int t = 0; t < TT; ++t) {
        const bool fin = (t == TT - 1);
        float4v acc[4];

        // -------- layer 0 MFMA: A from regs (tile 24 from LDS, wave 7), 4 kt --------
        #pragma unroll
        for (int mi = 0; mi < 4; ++mi) acc[mi] = (float4v){0,0,0,0};
        #pragma unroll
        for (int kt = 0; kt < 4; ++kt) {
            const short8v bf = *(const short8v*)(X0 + ((size_t)kt * 64 + lane) * 8);
            #pragma unroll
            for (int mi = 0; mi < 3; ++mi)
                acc[mi] = __builtin_amdgcn_mfma_f32_16x16x32_bf16(wr0[mi][kt], bf, acc[mi], 0, 0, 0);
            if (w7) {
                const short8v a = *(const short8v*)(A24 + ((size_t)kt * 64 + lane) * 8);
                acc[3] = __builtin_amdgcn_mfma_f32_16x16x32_bf16(a, bf, acc[3], 0, 0, 0);
            }
        }
        __syncthreads();   // A: X0 reads done

        // -------- layer 0 activation: h1(t) --------
        #pragma unroll
        for (int mi = 0; mi < 4; ++mi) {
            if (mi < 3 || w7) {
                const int cell = (mt0 + mi) * 4 + q;   // for w7/mi=3: tile 24
                const float iv = sigm_(acc[mi][0]);
                const float fv = sigm_(acc[mi][1]);
                const float gv = tanh_(acc[mi][2]);
                const float ov = sigm_(acc[mi][3]);
                const float c  = fv * c1[mi] + iv * gv;
                c1[mi] = c;
                const float h = ov * tanh_(c);
                const short hb = f2bf(h);
                { const int k = 18 + cell;   // X0 packed h1
                  X0[((k >> 5) * 64 + ((((k >> 3) & 3) << 4) | cl)) * 8 + (k & 7)] = hb; }
                { const int k = 4 + cell;    // X1 h1
                  X1[((k >> 5) * 64 + ((((k >> 3) & 3) << 4) | cl)) * 8 + (k & 7)] = hb; }
                if (fin) {
                    out[8064 + ((size_t)(n * 2 + 0) * 64 + b) * HH + cell] = h;
                    out[8064 + 1612800 + ((size_t)(n * 2 + 0) * 64 + b) * HH + cell] = c;
                }
            }
        }
        __syncthreads();   // B: h1 fragments visible

        // -------- layer 1 MFMA: A from regs (tile 24 from LDS, wave 7), 7 kt --------
        #pragma unroll
        for (int mi = 0; mi < 4; ++mi) acc[mi] = (float4v){0,0,0,0};
        #pragma unroll
        for (int kt = 0; kt < 7; ++kt) {
            const short8v bf = *(const short8v*)(X1 + ((size_t)kt * 64 + lane) * 8);
            #pragma unroll
            for (int mi = 0; mi < 3; ++mi)
                acc[mi] = __builtin_amdgcn_mfma_f32_16x16x32_bf16(wr1[mi][kt], bf, acc[mi], 0, 0, 0);
            if (w7) {
                const short8v a = *(const short8v*)(A24 + ((size_t)(4 + kt) * 64 + lane) * 8);
                acc[3] = __builtin_amdgcn_mfma_f32_16x16x32_bf16(a, bf, acc[3], 0, 0, 0);
            }
        }
        __syncthreads();   // C: X1 reads done

        // -------- layer 1 activation: h2(t); stage x(t+1) --------
        const float wet = wend[t];
        #pragma unroll
        for (int mi = 0; mi < 4; ++mi) {
            if (mi < 3 || w7) {
                const int cell = (mt0 + mi) * 4 + q;
                const float iv = sigm_(acc[mi][0]);
                const float fv = sigm_(acc[mi][1]);
                const float gv = tanh_(acc[mi][2]);
                const float ov = sigm_(acc[mi][3]);
                const float c  = fv * c2[mi] + iv * gv;
                c2[mi] = c;
                const float h = ov * tanh_(c);
                macc[mi] = fmaf(wet, h, macc[mi]);
                if (!fin) { const int k = 104 + cell;  // X1 h2
                  X1[((k >> 5) * 64 + ((((k >> 3) & 3) << 4) | cl)) * 8 + (k & 7)] = f2bf(h); }
                if (fin) {
                    out[8064 + ((size_t)(n * 2 + 1) * 64 + b) * HH + cell] = h;
                    out[8064 + 1612800 + ((size_t)(n * 2 + 1) * 64 + b) * HH + cell] = c;
                }
            }
        }
        stage_x(t + 1);
        __syncthreads();   // D: h2 / x visible for next step
    }

    // -------- epilogue: out[b,0,n,0] (red overlays X frags) --------
    #pragma unroll
    for (int mi = 0; mi < 4; ++mi) {
        if (mi < 3 || w7) {
            const int cell = (mt0 + mi) * 4 + q;
            red[cell * 16 + cl] = wlin[cell] * macc[mi];
        }
    }
    __syncthreads();
    if (tid < 16) {
        float s = 0.0f;
        for (int j = 0; j < HH; ++j) s += red[j * 16 + tid];
        float ws = 0.0f;
        for (int t2 = 0; t2 < TT; ++t2) ws += wend[t2];
        s += blin[0] * ws + bend[0];
        out[(size_t)(bq * 16 + tid) * NN + n] = s;
    }
}

// ================= fallback (R1 fp32 kernel, known-good) =================
#define BH 32
#define BPG 8
#define NTH 448

__global__ __launch_bounds__(NTH, 1)
void lstm_fused(const float* __restrict__ x,
                const float* __restrict__ Wih0, const float* __restrict__ Whh0,
                const float* __restrict__ bih0, const float* __restrict__ bhh0,
                const float* __restrict__ Wih1, const float* __restrict__ Whh1,
                const float* __restrict__ bih1, const float* __restrict__ bhh1,
                const float* __restrict__ wlin, const float* __restrict__ blin,
                const float* __restrict__ wend, const float* __restrict__ bend,
                float* __restrict__ out)
{
    const int n   = blockIdx.x >> 1;
    const int b0  = (blockIdx.x & 1) * BH;
    const int tid = threadIdx.x;
    const int j   = tid >> 2;
    const int bg  = tid & 3;
    const int bl0 = bg * BPG;
    const bool act = (j < HH);

    __shared__ float h1t[HH][BH];
    __shared__ float h2t[HH][BH];
    __shared__ float xt[FF][BH];
    __shared__ float red[HH][BH];

    for (int idx = tid; idx < HH * BH; idx += NTH) {
        (&h1t[0][0])[idx] = 0.0f;
        (&h2t[0][0])[idx] = 0.0f;
    }
    float c1[BPG], c2[BPG], macc[BPG];
    #pragma unroll
    for (int q = 0; q < BPG; ++q) { c1[q] = 0.0f; c2[q] = 0.0f; macc[q] = 0.0f; }

    float bs0[4], bs1[4];
    const float* wx0r[4];
    const float* w0r[4];
    const float* wi1r[4];
    const float* w1r[4];
    if (act) {
        #pragma unroll
        for (int g = 0; g < 4; ++g) {
            const int row = n * 400 + g * HH + j;
            bs0[g] = bih0[row] + bhh0[row];
            bs1[g] = bih1[row] + bhh1[row];
            wx0r[g] = Wih0 + (size_t)row * FF;
            w0r[g]  = Whh0 + (size_t)row * HH;
            wi1r[g] = Wih1 + (size_t)row * HH;
            w1r[g]  = Whh1 + (size_t)row * HH;
        }
    }
    __syncthreads();

    for (int t = 0; t < TT; ++t) {
        for (int idx = tid; idx < FF * BH; idx += NTH) {
            const int f = idx >> 5, bl = idx & 31;
            xt[f][bl] = x[(((b0 + bl) * TT + t) * NN + n) * FF + f];
        }
        __syncthreads();

        float ga[4][BPG];
        if (act) {
            #pragma unroll
            for (int g = 0; g < 4; ++g)
                #pragma unroll
                for (int q = 0; q < BPG; ++q) ga[g][q] = bs0[g];
            for (int f = 0; f < FF; ++f) {
                float wv[4];
                #pragma unroll
                for (int g = 0; g < 4; ++g) wv[g] = wx0r[g][f];
                #pragma unroll
                for (int q = 0; q < BPG; ++q) {
                    const float xv = xt[f][bl0 + q];
                    #pragma unroll
                    for (int g = 0; g < 4; ++g) ga[g][q] = fmaf(wv[g], xv, ga[g][q]);
                }
            }
            for (int k = 0; k < HH; k += 4) {
                float wg[4][4];
                #pragma unroll
                for (int g = 0; g < 4; ++g) {
                    const float4 wv = *(const float4*)(w0r[g] + k);
                    wg[g][0] = wv.x; wg[g][1] = wv.y; wg[g][2] = wv.z; wg[g][3] = wv.w;
                }
                #pragma unroll
                for (int kk = 0; kk < 4; ++kk) {
                    const float4* hr = (const float4*)(&h1t[k + kk][bl0]);
                    const float4 ha = hr[0], hb2 = hr[1];
                    const float hv[BPG] = {ha.x, ha.y, ha.z, ha.w, hb2.x, hb2.y, hb2.z, hb2.w};
                    #pragma unroll
                    for (int q = 0; q < BPG; ++q)
                        #pragma unroll
                        for (int g = 0; g < 4; ++g)
                            ga[g][q] = fmaf(wg[g][kk], hv[q], ga[g][q]);
                }
            }
        }
        __syncthreads();
        if (act) {
            #pragma unroll
            for (int q = 0; q < BPG; ++q) {
                const float iv = sigmf(ga[0][q]);
                const float fv = sigmf(ga[1][q]);
                const float gv = tanhf_(ga[2][q]);
                const float ov = sigmf(ga[3][q]);
                const float c  = fv * c1[q] + iv * gv;
                c1[q] = c;
                h1t[j][bl0 + q] = ov * tanhf_(c);
            }
        }
        __syncthreads();
        if (act) {
            #pragma unroll
            for (int g = 0; g < 4; ++g)
                #pragma unroll
                for (int q = 0; q < BPG; ++q) ga[g][q] = bs1[g];
            for (int k = 0; k < HH; k += 4) {
                float wg[4][4];
                #pragma unroll
                for (int g = 0; g < 4; ++g) {
                    const float4 wv = *(const float4*)(wi1r[g] + k);
                    wg[g][0] = wv.x; wg[g][1] = wv.y; wg[g][2] = wv.z; wg[g][3] = wv.w;
                }
                #pragma unroll
                for (int kk = 0; kk < 4; ++kk) {
                    const float4* hr = (const float4*)(&h1t[k + kk][bl0]);
                    const float4 ha = hr[0], hb2 = hr[1];
                    const float hv[BPG] = {ha.x, ha.y, ha.z, ha.w, hb2.x, hb2.y, hb2.z, hb2.w};
                    #pragma unroll
                    for (int q = 0; q < BPG; ++q)
                        #pragma unroll
                        for (int g = 0; g < 4; ++g)
                            ga[g][q] = fmaf(wg[g][kk], hv[q], ga[g][q]);
                }
            }
            for (int k = 0; k < HH; k += 4) {
                float wg[4][4];
                #pragma unroll
                for (int g = 0; g < 4; ++g) {
                    const float4 wv = *(const float4*)(w1r[g] + k);
                    wg[g][0] = wv.x; wg[g][1] = wv.y; wg[g][2] = wv.z; wg[g][3] = wv.w;
                }
                #pragma unroll
                for (int kk = 0; kk < 4; ++kk) {
                    const float4* hr = (const float4*)(&h2t[k + kk][bl0]);
                    const float4 ha = hr[0], hb2 = hr[1];
                    const float hv[BPG] = {ha.x, ha.y, ha.z, ha.w, hb2.x, hb2.y, hb2.z, hb2.w};
                    #pragma unroll
                    for (int q = 0; q < BPG; ++q)
                        #pragma unroll
                        for (int g = 0; g < 4; ++g)
                            ga[g][q] = fmaf(wg[g][kk], hv[q], ga[g][q]);
                }
            }
        }
        __syncthreads();
        const float wet = wend[t];
        if (act) {
            #pragma unroll
            for (int q = 0; q < BPG; ++q) {
                const float iv = sigmf(ga[0][q]);
                const float fv = sigmf(ga[1][q]);
                const float gv = tanhf_(ga[2][q]);
                const float ov = sigmf(ga[3][q]);
                const float c  = fv * c2[q] + iv * gv;
                c2[q] = c;
                const float h = ov * tanhf_(c);
                h2t[j][bl0 + q] = h;
                macc[q] = fmaf(wet, h, macc[q]);
            }
        }
    }

    if (act) {
        #pragma unroll
        for (int q = 0; q < BPG; ++q) {
            const int b = b0 + bl0 + q;
            const size_t hbase = 8064 + (size_t)n * 12800 + (size_t)b * HH + j;
            out[hbase]                  = h1t[j][bl0 + q];
            out[hbase + 6400]           = h2t[j][bl0 + q];
            out[hbase + 1612800]        = c1[q];
            out[hbase + 6400 + 1612800] = c2[q];
            red[j][bl0 + q] = wlin[j] * macc[q];
        }
    }
    __syncthreads();
    if (tid < BH) {
        float s = 0.0f;
        for (int jj = 0; jj < HH; ++jj) s += red[jj][tid];
        float ws = 0.0f;
        for (int t2 = 0; t2 < TT; ++t2) ws += wend[t2];
        s += blin[0] * ws + bend[0];
        out[(size_t)(b0 + tid) * NN + n] = s;
    }
}

extern "C" void kernel_launch(void* const* d_in, const int* in_sizes, int n_in,
                              void* d_out, int out_size, void* d_ws, size_t ws_size,
                              hipStream_t stream) {
    const float* x    = (const float*)d_in[0];
    const float* Wih0 = (const float*)d_in[1];
    const float* Whh0 = (const float*)d_in[2];
    const float* bih0 = (const float*)d_in[3];
    const float* bhh0 = (const float*)d_in[4];
    const float* Wih1 = (const float*)d_in[5];
    const float* Whh1 = (const float*)d_in[6];
    const float* bih1 = (const float*)d_in[7];
    const float* bhh1 = (const float*)d_in[8];
    const float* wlin = (const float*)d_in[9];
    const float* blin = (const float*)d_in[10];
    const float* wend = (const float*)d_in[11];
    const float* bend = (const float*)d_in[12];

    if (ws_size < WS_NEEDED) {
        lstm_fused<<<dim3(NN * 2), dim3(NTH), 0, stream>>>(
            x, Wih0, Whh0, bih0, bhh0, Wih1, Whh1, bih1, bhh1,
            wlin, blin, wend, bend, (float*)d_out);
        return;
    }

    short* wfrag = (short*)d_ws;
    short* xfrag = wfrag + WFRAG_ELEMS;

    prep_all<<<dim3(PW_BLOCKS + PX_BLOCKS), dim3(256), 0, stream>>>(
        Wih0, Whh0, bih0, bhh0, Wih1, Whh1, bih1, bhh1, x, wfrag, xfrag);
    lstm_mfma6<<<dim3(NN * 4), dim3(512), 0, stream>>>(
        wfrag, xfrag, wlin, blin, wend, bend, (float*)d_out);
}

// Round 8
// 138.648 us; speedup vs baseline: 2.2754x; 2.2754x over previous
//
#include <hip/hip_runtime.h>
#include <hip/hip_bf16.h>

#define NN 126   // nodes
#define TT 24    // seq len
#define FF 17    // input feat
#define HH 100   // hidden

// ---------- MFMA fragment geometry (identical to R5) ----------
//  L0, kt 0..3  (K=128): k<17 x | k==17 bias | k=18+j h1 | pad 118..127
//  L1, kt 4..10 (K=224): k==0 ones(bias) | pad 1..3 | k=4+j h1 | k=104+j h2 | pad
#define NKT 11
#define NMT 25
#define PER_NODE (NKT * NMT * 512)                  // 140,800 bf16 per node
#define WFRAG_ELEMS ((size_t)NN * PER_NODE)         // 17,740,800
#define XFRAG_ELEMS ((size_t)NN * TT * 4 * 64 * 8)  // 6,193,152
#define WS_NEEDED ((WFRAG_ELEMS + XFRAG_ELEMS) * 2) // 47,867,904 B

typedef __attribute__((ext_vector_type(8))) short short8v;
typedef __attribute__((ext_vector_type(4))) float float4v;

__device__ __forceinline__ short f2bf(float f) {
    union { float f; unsigned u; } v; v.f = f;
    unsigned r = v.u + 0x7FFFu + ((v.u >> 16) & 1u);   // RNE
    return (short)(r >> 16);
}
#define LOG2E 1.4426950408889634f
__device__ __forceinline__ float sigm_(float x) {
    return __builtin_amdgcn_rcpf(1.0f + __builtin_amdgcn_exp2f(-LOG2E * x));
}
__device__ __forceinline__ float tanh_(float x) {
    return 1.0f - 2.0f * __builtin_amdgcn_rcpf(1.0f + __builtin_amdgcn_exp2f((2.0f * LOG2E) * x));
}
// exact versions for the fallback kernel
__device__ __forceinline__ float sigmf(float x) { return 1.0f / (1.0f + __expf(-x)); }
__device__ __forceinline__ float tanhf_(float x) { return 2.0f / (1.0f + __expf(-2.0f * x)) - 1.0f; }

// ---------------- merged prep: weights + x -> bf16 MFMA fragments ----------------
#define PW_THREADS (NN * NKT * NMT * 64)            // 2,217,600
#define PX_THREADS (NN * TT * 4 * 64)               // 774,144
#define PW_BLOCKS ((PW_THREADS + 255) / 256)
#define PX_BLOCKS ((PX_THREADS + 255) / 256)

__global__ void prep_all(const float* __restrict__ Wih0, const float* __restrict__ Whh0,
                         const float* __restrict__ bih0, const float* __restrict__ bhh0,
                         const float* __restrict__ Wih1, const float* __restrict__ Whh1,
                         const float* __restrict__ bih1, const float* __restrict__ bhh1,
                         const float* __restrict__ x,
                         short* __restrict__ wfrag, short* __restrict__ xfrag)
{
    if (blockIdx.x < PW_BLOCKS) {
        const int idx = blockIdx.x * 256 + threadIdx.x;
        if (idx >= PW_THREADS) return;
        const int lane = idx & 63;
        int r = idx >> 6;
        const int mt = r % NMT; r /= NMT;
        const int kt = r % NKT;
        const int n  = r / NKT;

        const int row16 = lane & 15, kq = lane >> 4;
        const int gr = mt * 16 + row16;
        const int cell = gr >> 2, g = gr & 3;
        const int orow = n * 400 + g * HH + cell;   // gate blocks i,f,g,o

        short8v pv;
        #pragma unroll
        for (int e = 0; e < 8; ++e) {
            const int kk = kq * 8 + e;
            float f = 0.0f;
            if (kt < 4) {                           // L0 packed
                const int k = kt * 32 + kk;
                if (k < FF)        f = Wih0[(size_t)orow * FF + k];
                else if (k == FF)  f = bih0[orow] + bhh0[orow];
                else { const int j = k - 18; if (j < HH) f = Whh0[(size_t)orow * HH + j]; }
            } else {                                // L1
                const int k = (kt - 4) * 32 + kk;
                if (k == 0)                       f = bih1[orow] + bhh1[orow];
                else if (k >= 4 && k < 4 + HH)    f = Wih1[(size_t)orow * HH + (k - 4)];
                else if (k >= 104 && k < 104+HH)  f = Whh1[(size_t)orow * HH + (k - 104)];
            }
            pv[e] = f2bf(f);
        }
        *(short8v*)(wfrag + (size_t)idx * 8) = pv;
    } else {
        const int idx = (blockIdx.x - PW_BLOCKS) * 256 + threadIdx.x;
        if (idx >= PX_THREADS) return;
        const int lane = idx & 63;
        int r = idx >> 6;
        const int bq = r & 3; r >>= 2;
        const int t = r % TT;
        const int n = r / TT;
        const int b = bq * 16 + (lane & 15);
        const int kq = lane >> 4;

        short8v pv;
        #pragma unroll
        for (int e = 0; e < 8; ++e) {
            const int k = kq * 8 + e;
            float f = 0.0f;
            if (k < FF)       f = x[(((size_t)b * TT + t) * NN + n) * FF + k];
            else if (k == FF) f = 1.0f;
            pv[e] = f2bf(f);
        }
        *(short8v*)(xfrag + (size_t)idx * 8) = pv;
    }
}

// ---------------- main: 16-wave, 2-barrier double-buffered MFMA LSTM ----------------
// LDS (shorts): Al[4kt][25mt][64][8] = 51200 | X0[2buf][4kt][2nh][64][8] = 2*4096
//             | X1[2buf][7kt][2nh][64][8] = 2*7168      total 73728 shorts = 147,456 B
#define AL_SH 51200
#define X0_SH (AL_SH)
#define X1_SH (AL_SH + 8192)
#define X0BUF 4096
#define X1BUF 7168
#define LDS_BYTES ((X1_SH + 2 * X1BUF) * 2)

__global__ __launch_bounds__(1024, 4)
void lstm_mfma7(const short* __restrict__ wfrag, const short* __restrict__ xfrag,
                const float* __restrict__ wlin, const float* __restrict__ blin,
                const float* __restrict__ wend, const float* __restrict__ bend,
                float* __restrict__ out)
{
    extern __shared__ short lds_s[];
    short* Al = lds_s;                 // L0 weights [kt][mt][lane][e]
    short* X0 = lds_s + X0_SH;         // [buf][kt][nh][lane][e]
    short* X1 = lds_s + X1_SH;         // [buf][kt][nh][lane][e]; h1/ones only in buf0
    float* red = (float*)lds_s;        // overlay over Al, epilogue only

    const int n   = blockIdx.x >> 1;
    const int bh  = blockIdx.x & 1;                 // batch half (32 each)
    const int tid = threadIdx.x, lane = tid & 63, w = tid >> 6;   // 16 waves
    const int cl  = lane & 15, q = lane >> 4;
    const int mt0 = (w <= 8) ? (w * 2) : (18 + (w - 9));  // waves 0..8: 2 tiles; 9..15: 1
    const int nmt = (w <= 8) ? 2 : 1;

    const short* wnode = wfrag + (size_t)n * PER_NODE;

    // ---- init: zero both X0/X1 buffers; stage L0 weights -> LDS; L1 weights -> regs ----
    {
        const short8v z = {0,0,0,0,0,0,0,0};
        for (int i = tid; i < (2 * X0BUF + 2 * X1BUF) / 8; i += 1024)
            *(short8v*)(X0 + (size_t)i * 8) = z;
    }
    for (int i = tid; i < 4 * NMT * 64; i += 1024)
        *(short8v*)(Al + (size_t)i * 8) = *(const short8v*)(wnode + (size_t)i * 8);

    short8v wreg[2][7];                             // L1 weights, kt 4..10
    #pragma unroll
    for (int mi = 0; mi < 2; ++mi) {
        if (mi < nmt) {
            #pragma unroll
            for (int kt = 0; kt < 7; ++kt)
                wreg[mi][kt] = *(const short8v*)(
                    wnode + (((size_t)(4 + kt) * NMT + (mt0 + mi)) * 64 + lane) * 8);
        }
    }

    // hoisted per-thread LDS scatter element-offsets (within a buffer)
    int aX0h1[2][2], aX1h1[2][2], aX1h2[2][2];
    #pragma unroll
    for (int mi = 0; mi < 2; ++mi) {
        const int cell = (mt0 + mi) * 4 + q;
        #pragma unroll
        for (int nh = 0; nh < 2; ++nh) {
            { const int k = 18 + cell;
              aX0h1[mi][nh] = (((k >> 5) * 2 + nh) * 64 + ((((k >> 3) & 3) << 4) | cl)) * 8 + (k & 7); }
            { const int k = 4 + cell;
              aX1h1[mi][nh] = (((k >> 5) * 2 + nh) * 64 + ((((k >> 3) & 3) << 4) | cl)) * 8 + (k & 7); }
            { const int k = 104 + cell;
              aX1h2[mi][nh] = (((k >> 5) * 2 + nh) * 64 + ((((k >> 3) & 3) << 4) | cl)) * 8 + (k & 7); }
        }
    }
    __syncthreads();
    // ones column for L1 bias (k=0 -> kt0, kq=0, e=0, cols 0..15, both nh) -- buf0 only
    if (tid < 32) X1[(((tid >> 4)) * 64 + (tid & 15)) * 8 + 0] = (short)0x3F80;
    // x(0) -> buf0; writes ONLY k=0..17 of kt0 (k>=18 holds packed h1)
    if (w < 2) {
        const short8v v = *(const short8v*)(
            xfrag + ((((size_t)n * TT + 0) * 4 + (bh * 2 + w)) * 64 + lane) * 8);
        if (q < 2)       *(short8v*)(X0 + ((size_t)w * 64 + lane) * 8) = v;
        else if (q == 2) *(int*)(X0 + ((size_t)w * 64 + lane) * 8) = *(const int*)&v;
    }
    __syncthreads();

    float c1[2][2], c2[2][2], macc[2][2];
    #pragma unroll
    for (int mi = 0; mi < 2; ++mi)
        #pragma unroll
        for (int nh = 0; nh < 2; ++nh) { c1[mi][nh] = 0.f; c2[mi][nh] = 0.f; macc[mi][nh] = 0.f; }

    for (int t = 0; t < TT; ++t) {
        const bool fin = (t == TT - 1);
        const int rb = t & 1;                  // read buffer (X0 full; X1.h2)
        const int wb = rb ^ 1;                 // write buffer
        float4v acc[2][2];

        // ======== PHASE A: L0 MFMA (reads X0[rb], Al) + L0 act (writes X0[wb].h1, X1[0].h1) ========
        #pragma unroll
        for (int mi = 0; mi < 2; ++mi) { acc[mi][0] = (float4v){0,0,0,0}; acc[mi][1] = (float4v){0,0,0,0}; }
        {
            const short* X0r = X0 + rb * X0BUF;
            #pragma unroll
            for (int kt = 0; kt < 4; ++kt) {
                const short8v b0 = *(const short8v*)(X0r + (((size_t)kt * 2 + 0) * 64 + lane) * 8);
                const short8v b1 = *(const short8v*)(X0r + (((size_t)kt * 2 + 1) * 64 + lane) * 8);
                #pragma unroll
                for (int mi = 0; mi < 2; ++mi) {
                    if (mi < nmt) {
                        const short8v a = *(const short8v*)(
                            Al + (((size_t)kt * NMT + (mt0 + mi)) * 64 + lane) * 8);
                        acc[mi][0] = __builtin_amdgcn_mfma_f32_16x16x32_bf16(a, b0, acc[mi][0], 0, 0, 0);
                        acc[mi][1] = __builtin_amdgcn_mfma_f32_16x16x32_bf16(a, b1, acc[mi][1], 0, 0, 0);
                    }
                }
            }
        }
        #pragma unroll
        for (int mi = 0; mi < 2; ++mi) {
            if (mi < nmt) {
                const int cell = (mt0 + mi) * 4 + q;
                #pragma unroll
                for (int nh = 0; nh < 2; ++nh) {
                    const float iv = sigm_(acc[mi][nh][0]);
                    const float fv = sigm_(acc[mi][nh][1]);
                    const float gv = tanh_(acc[mi][nh][2]);
                    const float ov = sigm_(acc[mi][nh][3]);
                    const float c  = fv * c1[mi][nh] + iv * gv;
                    c1[mi][nh] = c;
                    const float h = ov * tanh_(c);
                    const short hb = f2bf(h);
                    X0[wb * X0BUF + aX0h1[mi][nh]] = hb;   // h1(t) for next step's L0
                    X1[aX1h1[mi][nh]] = hb;                // h1(t) for this step's L1 (buf0)
                    if (fin) {
                        const int b = bh * 32 + nh * 16 + cl;
                        out[8064 + ((size_t)(n * 2 + 0) * 64 + b) * HH + cell] = h;
                        out[8064 + 1612800 + ((size_t)(n * 2 + 0) * 64 + b) * HH + cell] = c;
                    }
                }
            }
        }
        __syncthreads();   // BARRIER 1: h1(t) visible; X0[rb]/X1-h2[rb] reads all issued? (reads were phase A / prev iter)

        // ======== PHASE B: L1 MFMA (reads X1[0].h1, X1[rb].h2) + L1 act (writes X1[wb].h2) + x stage ========
        #pragma unroll
        for (int mi = 0; mi < 2; ++mi) { acc[mi][0] = (float4v){0,0,0,0}; acc[mi][1] = (float4v){0,0,0,0}; }
        {
            const short* X1h2 = X1 + rb * X1BUF;
            const int kt3sel = (q == 0) ? 0 : rb * X1BUF;   // kt3: kq0 = h1 (buf0), kq1-3 = h2 (rb)
            #pragma unroll
            for (int kt = 0; kt < 7; ++kt) {
                const short* base = (kt < 3) ? X1 : ((kt == 3) ? (X1 + kt3sel) : X1h2);
                const short8v b0 = *(const short8v*)(base + (((size_t)kt * 2 + 0) * 64 + lane) * 8);
                const short8v b1 = *(const short8v*)(base + (((size_t)kt * 2 + 1) * 64 + lane) * 8);
                #pragma unroll
                for (int mi = 0; mi < 2; ++mi) {
                    if (mi < nmt) {
                        acc[mi][0] = __builtin_amdgcn_mfma_f32_16x16x32_bf16(wreg[mi][kt], b0, acc[mi][0], 0, 0, 0);
                        acc[mi][1] = __builtin_amdgcn_mfma_f32_16x16x32_bf16(wreg[mi][kt], b1, acc[mi][1], 0, 0, 0);
                    }
                }
            }
        }
        const float wet = wend[t];
        #pragma unroll
        for (int mi = 0; mi < 2; ++mi) {
            if (mi < nmt) {
                const int cell = (mt0 + mi) * 4 + q;
                #pragma unroll
                for (int nh = 0; nh < 2; ++nh) {
                    const float iv = sigm_(acc[mi][nh][0]);
                    const float fv = sigm_(acc[mi][nh][1]);
                    const float gv = tanh_(acc[mi][nh][2]);
                    const float ov = sigm_(acc[mi][nh][3]);
                    const float c  = fv * c2[mi][nh] + iv * gv;
                    c2[mi][nh] = c;
                    const float h = ov * tanh_(c);
                    macc[mi][nh] = fmaf(wet, h, macc[mi][nh]);
                    if (!fin) X1[wb * X1BUF + aX1h2[mi][nh]] = f2bf(h);   // h2(t) -> write buf
                    if (fin) {
                        const int b = bh * 32 + nh * 16 + cl;
                        out[8064 + ((size_t)(n * 2 + 1) * 64 + b) * HH + cell] = h;
                        out[8064 + 1612800 + ((size_t)(n * 2 + 1) * 64 + b) * HH + cell] = c;
                    }
                }
            }
        }
        // stage x(t+1) into X0[wb] (k0..17 of kt0 only; h1(t) already sits at k>=18 of wb)
        if (w < 2 && t + 1 < TT) {
            const short8v v = *(const short8v*)(
                xfrag + ((((size_t)n * TT + (t + 1)) * 4 + (bh * 2 + w)) * 64 + lane) * 8);
            short* X0w = X0 + wb * X0BUF;
            if (q < 2)       *(short8v*)(X0w + ((size_t)w * 64 + lane) * 8) = v;
            else if (q == 2) *(int*)(X0w + ((size_t)w * 64 + lane) * 8) = *(const int*)&v;
        }
        __syncthreads();   // BARRIER 2: h2(t) / x(t+1) visible
    }

    // -------- epilogue: out[b,0,n,0] (red overlays Al) --------
    #pragma unroll
    for (int mi = 0; mi < 2; ++mi) {
        if (mi < nmt) {
            const int cell = (mt0 + mi) * 4 + q;
            #pragma unroll
            for (int nh = 0; nh < 2; ++nh)
                red[cell * 32 + nh * 16 + cl] = wlin[cell] * macc[mi][nh];
        }
    }
    __syncthreads();
    if (tid < 32) {
        float s = 0.0f;
        for (int j = 0; j < HH; ++j) s += red[j * 32 + tid];
        float ws = 0.0f;
        for (int t2 = 0; t2 < TT; ++t2) ws += wend[t2];
        s += blin[0] * ws + bend[0];
        out[(size_t)(bh * 32 + tid) * NN + n] = s;
    }
}

// ================= fallback (R1 fp32 kernel, known-good) =================
#define BH 32
#define BPG 8
#define NTH 448

__global__ __launch_bounds__(NTH, 1)
void lstm_fused(const float* __restrict__ x,
                const float* __restrict__ Wih0, const float* __restrict__ Whh0,
                const float* __restrict__ bih0, const float* __restrict__ bhh0,
                const float* __restrict__ Wih1, const float* __restrict__ Whh1,
                const float* __restrict__ bih1, const float* __restrict__ bhh1,
                const float* __restrict__ wlin, const float* __restrict__ blin,
                const float* __restrict__ wend, const float* __restrict__ bend,
                float* __restrict__ out)
{
    const int n   = blockIdx.x >> 1;
    const int b0  = (blockIdx.x & 1) * BH;
    const int tid = threadIdx.x;
    const int j   = tid >> 2;
    const int bg  = tid & 3;
    const int bl0 = bg * BPG;
    const bool act = (j < HH);

    __shared__ float h1t[HH][BH];
    __shared__ float h2t[HH][BH];
    __shared__ float xt[FF][BH];
    __shared__ float red[HH][BH];

    for (int idx = tid; idx < HH * BH; idx += NTH) {
        (&h1t[0][0])[idx] = 0.0f;
        (&h2t[0][0])[idx] = 0.0f;
    }
    float c1[BPG], c2[BPG], macc[BPG];
    #pragma unroll
    for (int q = 0; q < BPG; ++q) { c1[q] = 0.0f; c2[q] = 0.0f; macc[q] = 0.0f; }

    float bs0[4], bs1[4];
    const float* wx0r[4];
    const float* w0r[4];
    const float* wi1r[4];
    const float* w1r[4];
    if (act) {
        #pragma unroll
        for (int g = 0; g < 4; ++g) {
            const int row = n * 400 + g * HH + j;
            bs0[g] = bih0[row] + bhh0[row];
            bs1[g] = bih1[row] + bhh1[row];
            wx0r[g] = Wih0 + (size_t)row * FF;
            w0r[g]  = Whh0 + (size_t)row * HH;
            wi1r[g] = Wih1 + (size_t)row * HH;
            w1r[g]  = Whh1 + (size_t)row * HH;
        }
    }
    __syncthreads();

    for (int t = 0; t < TT; ++t) {
        for (int idx = tid; idx < FF * BH; idx += NTH) {
            const int f = idx >> 5, bl = idx & 31;
            xt[f][bl] = x[(((b0 + bl) * TT + t) * NN + n) * FF + f];
        }
        __syncthreads();

        float ga[4][BPG];
        if (act) {
            #pragma unroll
            for (int g = 0; g < 4; ++g)
                #pragma unroll
                for (int q = 0; q < BPG; ++q) ga[g][q] = bs0[g];
            for (int f = 0; f < FF; ++f) {
                float wv[4];
                #pragma unroll
                for (int g = 0; g < 4; ++g) wv[g] = wx0r[g][f];
                #pragma unroll
                for (int q = 0; q < BPG; ++q) {
                    const float xv = xt[f][bl0 + q];
                    #pragma unroll
                    for (int g = 0; g < 4; ++g) ga[g][q] = fmaf(wv[g], xv, ga[g][q]);
                }
            }
            for (int k = 0; k < HH; k += 4) {
                float wg[4][4];
                #pragma unroll
                for (int g = 0; g < 4; ++g) {
                    const float4 wv = *(const float4*)(w0r[g] + k);
                    wg[g][0] = wv.x; wg[g][1] = wv.y; wg[g][2] = wv.z; wg[g][3] = wv.w;
                }
                #pragma unroll
                for (int kk = 0; kk < 4; ++kk) {
                    const float4* hr = (const float4*)(&h1t[k + kk][bl0]);
                    const float4 ha = hr[0], hb2 = hr[1];
                    const float hv[BPG] = {ha.x, ha.y, ha.z, ha.w, hb2.x, hb2.y, hb2.z, hb2.w};
                    #pragma unroll
                    for (int q = 0; q < BPG; ++q)
                        #pragma unroll
                        for (int g = 0; g < 4; ++g)
                            ga[g][q] = fmaf(wg[g][kk], hv[q], ga[g][q]);
                }
            }
        }
        __syncthreads();
        if (act) {
            #pragma unroll
            for (int q = 0; q < BPG; ++q) {
                const float iv = sigmf(ga[0][q]);
                const float fv = sigmf(ga[1][q]);
                const float gv = tanhf_(ga[2][q]);
                const float ov = sigmf(ga[3][q]);
                const float c  = fv * c1[q] + iv * gv;
                c1[q] = c;
                h1t[j][bl0 + q] = ov * tanhf_(c);
            }
        }
        __syncthreads();
        if (act) {
            #pragma unroll
            for (int g = 0; g < 4; ++g)
                #pragma unroll
                for (int q = 0; q < BPG; ++q) ga[g][q] = bs1[g];
            for (int k = 0; k < HH; k += 4) {
                float wg[4][4];
                #pragma unroll
                for (int g = 0; g < 4; ++g) {
                    const float4 wv = *(const float4*)(wi1r[g] + k);
                    wg[g][0] = wv.x; wg[g][1] = wv.y; wg[g][2] = wv.z; wg[g][3] = wv.w;
                }
                #pragma unroll
                for (int kk = 0; kk < 4; ++kk) {
                    const float4* hr = (const float4*)(&h1t[k + kk][bl0]);
                    const float4 ha = hr[0], hb2 = hr[1];
                    const float hv[BPG] = {ha.x, ha.y, ha.z, ha.w, hb2.x, hb2.y, hb2.z, hb2.w};
                    #pragma unroll
                    for (int q = 0; q < BPG; ++q)
                        #pragma unroll
                        for (int g = 0; g < 4; ++g)
                            ga[g][q] = fmaf(wg[g][kk], hv[q], ga[g][q]);
                }
            }
            for (int k = 0; k < HH; k += 4) {
                float wg[4][4];
                #pragma unroll
                for (int g = 0; g < 4; ++g) {
                    const float4 wv = *(const float4*)(w1r[g] + k);
                    wg[g][0] = wv.x; wg[g][1] = wv.y; wg[g][2] = wv.z; wg[g][3] = wv.w;
                }
                #pragma unroll
                for (int kk = 0; kk < 4; ++kk) {
                    const float4* hr = (const float4*)(&h2t[k + kk][bl0]);
                    const float4 ha = hr[0], hb2 = hr[1];
                    const float hv[BPG] = {ha.x, ha.y, ha.z, ha.w, hb2.x, hb2.y, hb2.z, hb2.w};
                    #pragma unroll
                    for (int q = 0; q < BPG; ++q)
                        #pragma unroll
                        for (int g = 0; g < 4; ++g)
                            ga[g][q] = fmaf(wg[g][kk], hv[q], ga[g][q]);
                }
            }
        }
        __syncthreads();
        const float wet = wend[t];
        if (act) {
            #pragma unroll
            for (int q = 0; q < BPG; ++q) {
                const float iv = sigmf(ga[0][q]);
                const float fv = sigmf(ga[1][q]);
                const float gv = tanhf_(ga[2][q]);
                const float ov = sigmf(ga[3][q]);
                const float c  = fv * c2[q] + iv * gv;
                c2[q] = c;
                const float h = ov * tanhf_(c);
                h2t[j][bl0 + q] = h;
                macc[q] = fmaf(wet, h, macc[q]);
            }
        }
    }

    if (act) {
        #pragma unroll
        for (int q = 0; q < BPG; ++q) {
            const int b = b0 + bl0 + q;
            const size_t hbase = 8064 + (size_t)n * 12800 + (size_t)b * HH + j;
            out[hbase]                  = h1t[j][bl0 + q];
            out[hbase + 6400]           = h2t[j][bl0 + q];
            out[hbase + 1612800]        = c1[q];
            out[hbase + 6400 + 1612800] = c2[q];
            red[j][bl0 + q] = wlin[j] * macc[q];
        }
    }
    __syncthreads();
    if (tid < BH) {
        float s = 0.0f;
        for (int jj = 0; jj < HH; ++jj) s += red[jj][tid];
        float ws = 0.0f;
        for (int t2 = 0; t2 < TT; ++t2) ws += wend[t2];
        s += blin[0] * ws + bend[0];
        out[(size_t)(b0 + tid) * NN + n] = s;
    }
}

extern "C" void kernel_launch(void* const* d_in, const int* in_sizes, int n_in,
                              void* d_out, int out_size, void* d_ws, size_t ws_size,
                              hipStream_t stream) {
    const float* x    = (const float*)d_in[0];
    const float* Wih0 = (const float*)d_in[1];
    const float* Whh0 = (const float*)d_in[2];
    const float* bih0 = (const float*)d_in[3];
    const float* bhh0 = (const float*)d_in[4];
    const float* Wih1 = (const float*)d_in[5];
    const float* Whh1 = (const float*)d_in[6];
    const float* bih1 = (const float*)d_in[7];
    const float* bhh1 = (const float*)d_in[8];
    const float* wlin = (const float*)d_in[9];
    const float* blin = (const float*)d_in[10];
    const float* wend = (const float*)d_in[11];
    const float* bend = (const float*)d_in[12];

    if (ws_size < WS_NEEDED) {
        lstm_fused<<<dim3(NN * 2), dim3(NTH), 0, stream>>>(
            x, Wih0, Whh0, bih0, bhh0, Wih1, Whh1, bih1, bhh1,
            wlin, blin, wend, bend, (float*)d_out);
        return;
    }

    short* wfrag = (short*)d_ws;
    short* xfrag = wfrag + WFRAG_ELEMS;

    prep_all<<<dim3(PW_BLOCKS + PX_BLOCKS), dim3(256), 0, stream>>>(
        Wih0, Whh0, bih0, bhh0, Wih1, Whh1, bih1, bhh1, x, wfrag, xfrag);
    lstm_mfma7<<<dim3(NN * 2), dim3(1024), LDS_BYTES, stream>>>(
        wfrag, xfrag, wlin, blin, wend, bend, (float*)d_out);
}

// Round 10
// 111.870 us; speedup vs baseline: 2.8201x; 1.2394x over previous
//
#include <hip/hip_runtime.h>
#include <hip/hip_bf16.h>

#define NN 126   // nodes
#define TT 24    // seq len
#define FF 17    // input feat
#define HH 100   // hidden
#define NMT 25   // M tiles (400 gate-interleaved rows)

// ---------- MFMA fragment geometry (identical to R5/R8) ----------
//  L0, kt 0..3  (K=128): k<17 Wih0 | k==17 bias0 | k=18+j Whh0 (j<100) | pad 118..127
//  L1, kt 0..6  (K=224): k==0 bias1(ones col) | pad 1..3 | k=4+j Wih1 | k=104+j Whh1 | pad 204..223
// LDS layout in shorts: Al[4][25][64][8]=51200 | X0[2buf][4kt][2nh][64][8]=8192 | X1[2buf][7kt][2nh][64][8]=14336
#define AL_SH 51200
#define X0_SH AL_SH
#define X1_SH (AL_SH + 8192)
#define X0BUF 4096
#define X1BUF 7168
#define TOT_SH (X1_SH + 2 * X1BUF)     // 73728 shorts
#define LDS_BYTES (TOT_SH * 2)         // 147,456 B

typedef __attribute__((ext_vector_type(8))) short short8v;
typedef __attribute__((ext_vector_type(4))) float float4v;

__device__ __forceinline__ short f2bf(float f) {
    union { float f; unsigned u; } v; v.f = f;
    unsigned r = v.u + 0x7FFFu + ((v.u >> 16) & 1u);   // RNE
    return (short)(r >> 16);
}
#define LOG2E 1.4426950408889634f
__device__ __forceinline__ float sigm_(float x) {
    return __builtin_amdgcn_rcpf(1.0f + __builtin_amdgcn_exp2f(-LOG2E * x));
}
__device__ __forceinline__ float tanh_(float x) {
    return 1.0f - 2.0f * __builtin_amdgcn_rcpf(1.0f + __builtin_amdgcn_exp2f((2.0f * LOG2E) * x));
}

// ---------------- fused: prep + 16-wave 2-barrier double-buffered MFMA LSTM ----------------
__global__ __launch_bounds__(1024, 4)
void lstm_one(const float* __restrict__ x,
              const float* __restrict__ Wih0, const float* __restrict__ Whh0,
              const float* __restrict__ bih0, const float* __restrict__ bhh0,
              const float* __restrict__ Wih1, const float* __restrict__ Whh1,
              const float* __restrict__ bih1, const float* __restrict__ bhh1,
              const float* __restrict__ wlin, const float* __restrict__ blin,
              const float* __restrict__ wend, const float* __restrict__ bend,
              float* __restrict__ out)
{
    extern __shared__ short lds_s[];
    short* Al = lds_s;                 // L0 weights [kt][mt][lane][e]
    short* X0 = lds_s + X0_SH;         // [buf][kt][nh][lane][e]
    short* X1 = lds_s + X1_SH;         // [buf][kt][nh][lane][e]; h1/ones only in buf0
    float* red = (float*)lds_s;        // overlay over Al, epilogue only

    const int n   = blockIdx.x >> 1;
    const int bh  = blockIdx.x & 1;                 // batch half (32 each)
    const int tid = threadIdx.x, lane = tid & 63, w = tid >> 6;   // 16 waves
    const int cl  = lane & 15, q = lane >> 4;
    const int mt0 = (w <= 8) ? (w * 2) : (18 + (w - 9));  // waves 0..8: 2 tiles; 9..15: 1
    const int nmt = (w <= 8) ? 2 : 1;

    // ---- init 0: zero Al + both X0/X1 buffers ----
    {
        const short8v zz = {0,0,0,0,0,0,0,0};
        for (int i = tid; i < TOT_SH / 8; i += 1024)
            *(short8v*)(lds_s + (size_t)i * 8) = zz;
    }
    __syncthreads();   // zeros visible before scatter-fill

    // ---- init 1: L0 weights -> Al (fp32 coalesced read, bf16 LDS scatter) ----
    {
        const float* W = Whh0 + (size_t)n * 40000;        // [orl 0..399][j 0..99], k = 18+j
        for (int i = tid; i < 40000; i += 1024) {
            const int orl = i / 100, j = i - orl * 100;
            const int g = orl / 100, cell = orl - g * 100;
            const int gr = cell * 4 + g;
            const int k = 18 + j;
            Al[(((k >> 5) * NMT + (gr >> 4)) * 64 + ((((k >> 3) & 3) << 4) | (gr & 15))) * 8 + (k & 7)]
                = f2bf(W[i]);
        }
    }
    {
        const float* W = Wih0 + (size_t)n * 6800;         // [orl][k 0..16], kt0
        for (int i = tid; i < 6800; i += 1024) {
            const int orl = i / 17, k = i - orl * 17;
            const int g = orl / 100, cell = orl - g * 100;
            const int gr = cell * 4 + g;
            Al[((gr >> 4) * 64 + ((((k >> 3) & 3) << 4) | (gr & 15))) * 8 + (k & 7)] = f2bf(W[i]);
        }
    }
    if (tid < 400) {                                      // L0 bias at k=17 (kt0, kq2, e1)
        const int g = tid / 100, cell = tid - g * 100;
        const int gr = cell * 4 + g;
        const int orow = n * 400 + tid;
        Al[((gr >> 4) * 64 + ((2 << 4) | (gr & 15))) * 8 + 1] = f2bf(bih0[orow] + bhh0[orow]);
    }

    // ---- init 2: L1 weights -> wreg (per-thread contiguous 32B gathers) ----
    short8v wreg[2][7];
    #pragma unroll
    for (int mi = 0; mi < 2; ++mi) {
        if (mi < nmt) {
            const int gr = (mt0 + mi) * 16 + cl;
            const int cell = gr >> 2, g = gr & 3;
            const int orow = n * 400 + g * HH + cell;
            const float* Wi = Wih1 + (size_t)orow * HH;
            const float* Wh = Whh1 + (size_t)orow * HH;
            #pragma unroll
            for (int kt = 0; kt < 7; ++kt) {
                const int k0 = kt * 32 + q * 8;           // chunk base, multiple of 8
                float v[8];
                #pragma unroll
                for (int e = 0; e < 8; ++e) v[e] = 0.0f;
                if (k0 == 0) {                            // mixed: bias | pad | Wih1 j0..3
                    v[0] = bih1[orow] + bhh1[orow];
                    v[4] = Wi[0]; v[5] = Wi[1]; v[6] = Wi[2]; v[7] = Wi[3];
                } else if (k0 <= 96) {                    // pure Wih1, j = k0-4+e
                    #pragma unroll
                    for (int e = 0; e < 8; ++e) v[e] = Wi[k0 - 4 + e];
                } else if (k0 >= 104 && k0 <= 192) {      // pure Whh1, j = k0-104+e
                    #pragma unroll
                    for (int e = 0; e < 8; ++e) v[e] = Wh[k0 - 104 + e];
                } else if (k0 == 200) {                   // mixed: Whh1 j96..99 | pad
                    v[0] = Wh[96]; v[1] = Wh[97]; v[2] = Wh[98]; v[3] = Wh[99];
                }
                short8v pv;
                #pragma unroll
                for (int e = 0; e < 8; ++e) pv[e] = f2bf(v[e]);
                wreg[mi][kt] = pv;
            }
        }
    }

    // hoisted per-thread LDS scatter element-offsets (within a buffer)
    int aX0h1[2][2], aX1h1[2][2], aX1h2[2][2];
    #pragma unroll
    for (int mi = 0; mi < 2; ++mi) {
        const int cell = (mt0 + mi) * 4 + q;
        #pragma unroll
        for (int nh = 0; nh < 2; ++nh) {
            { const int k = 18 + cell;
              aX0h1[mi][nh] = (((k >> 5) * 2 + nh) * 64 + ((((k >> 3) & 3) << 4) | cl)) * 8 + (k & 7); }
            { const int k = 4 + cell;
              aX1h1[mi][nh] = (((k >> 5) * 2 + nh) * 64 + ((((k >> 3) & 3) << 4) | cl)) * 8 + (k & 7); }
            { const int k = 104 + cell;
              aX1h2[mi][nh] = (((k >> 5) * 2 + nh) * 64 + ((((k >> 3) & 3) << 4) | cl)) * 8 + (k & 7); }
        }
    }
    __syncthreads();   // weight fill visible

    // ones column for L1 bias (k=0 -> kt0, kq=0, e=0, cols 0..15, both nh) -- buf0 only
    if (tid < 32) X1[(((tid >> 4)) * 64 + (tid & 15)) * 8 + 0] = (short)0x3F80;
    // x(0) -> X0 buf0 directly from global; nh = w; writes ONLY k=0..17 of kt0
    if (w < 2) {
        const int b = bh * 32 + w * 16 + cl;
        const float* xr = x + ((size_t)b * TT + 0) * (NN * FF) + n * FF;
        if (q < 2) {
            short8v pv;
            #pragma unroll
            for (int e = 0; e < 8; ++e) pv[e] = f2bf(xr[q * 8 + e]);
            *(short8v*)(X0 + ((size_t)w * 64 + lane) * 8) = pv;            // nh = w
        } else if (q == 2) {
            const unsigned lo = (unsigned short)f2bf(xr[16]);
            *(unsigned*)(X0 + ((size_t)w * 64 + lane) * 8) = (0x3F80u << 16) | lo;  // k16=x, k17=1.0
        }
    }
    __syncthreads();

    float c1[2][2], c2[2][2], macc[2][2];
    #pragma unroll
    for (int mi = 0; mi < 2; ++mi)
        #pragma unroll
        for (int nh = 0; nh < 2; ++nh) { c1[mi][nh] = 0.f; c2[mi][nh] = 0.f; macc[mi][nh] = 0.f; }

    for (int t = 0; t < TT; ++t) {
        const bool fin = (t == TT - 1);
        const int rb = t & 1;                  // read buffer (X0 full; X1.h2)
        const int wb = rb ^ 1;                 // write buffer
        float4v acc[2][2];

        // ======== PHASE A: L0 MFMA (reads X0[rb], Al) + L0 act (writes X0[wb].h1, X1[0].h1) ========
        #pragma unroll
        for (int mi = 0; mi < 2; ++mi) { acc[mi][0] = (float4v){0,0,0,0}; acc[mi][1] = (float4v){0,0,0,0}; }
        {
            const short* X0r = X0 + rb * X0BUF;
            #pragma unroll
            for (int kt = 0; kt < 4; ++kt) {
                const short8v b0 = *(const short8v*)(X0r + (((size_t)kt * 2 + 0) * 64 + lane) * 8);
                const short8v b1 = *(const short8v*)(X0r + (((size_t)kt * 2 + 1) * 64 + lane) * 8);
                #pragma unroll
                for (int mi = 0; mi < 2; ++mi) {
                    if (mi < nmt) {
                        const short8v a = *(const short8v*)(
                            Al + (((size_t)kt * NMT + (mt0 + mi)) * 64 + lane) * 8);
                        acc[mi][0] = __builtin_amdgcn_mfma_f32_16x16x32_bf16(a, b0, acc[mi][0], 0, 0, 0);
                        acc[mi][1] = __builtin_amdgcn_mfma_f32_16x16x32_bf16(a, b1, acc[mi][1], 0, 0, 0);
                    }
                }
            }
        }
        #pragma unroll
        for (int mi = 0; mi < 2; ++mi) {
            if (mi < nmt) {
                const int cell = (mt0 + mi) * 4 + q;
                #pragma unroll
                for (int nh = 0; nh < 2; ++nh) {
                    const float iv = sigm_(acc[mi][nh][0]);
                    const float fv = sigm_(acc[mi][nh][1]);
                    const float gv = tanh_(acc[mi][nh][2]);
                    const float ov = sigm_(acc[mi][nh][3]);
                    const float c  = fv * c1[mi][nh] + iv * gv;
                    c1[mi][nh] = c;
                    const float h = ov * tanh_(c);
                    const short hb = f2bf(h);
                    X0[wb * X0BUF + aX0h1[mi][nh]] = hb;   // h1(t) for next step's L0
                    X1[aX1h1[mi][nh]] = hb;                // h1(t) for this step's L1 (buf0)
                    if (fin) {
                        const int b = bh * 32 + nh * 16 + cl;
                        out[8064 + ((size_t)(n * 2 + 0) * 64 + b) * HH + cell] = h;
                        out[8064 + 1612800 + ((size_t)(n * 2 + 0) * 64 + b) * HH + cell] = c;
                    }
                }
            }
        }
        __syncthreads();   // BARRIER 1: h1(t) visible

        // early issue: x(t+1) global loads into regs (written to LDS after L1 act)
        float xv0 = 0.f, xv1 = 0.f, xv2 = 0.f, xv3 = 0.f, xv4 = 0.f, xv5 = 0.f, xv6 = 0.f, xv7 = 0.f;
        const bool doX = (w < 2) && (t + 1 < TT);
        if (doX) {
            const int b = bh * 32 + w * 16 + cl;
            const float* xr = x + ((size_t)b * TT + (t + 1)) * (NN * FF) + n * FF;
            if (q < 2) {
                const int k0 = q * 8;
                xv0 = xr[k0 + 0]; xv1 = xr[k0 + 1]; xv2 = xr[k0 + 2]; xv3 = xr[k0 + 3];
                xv4 = xr[k0 + 4]; xv5 = xr[k0 + 5]; xv6 = xr[k0 + 6]; xv7 = xr[k0 + 7];
            } else if (q == 2) {
                xv0 = xr[16];
            }
        }

        // ======== PHASE B: L1 MFMA (reads X1[0].h1, X1[rb].h2) + L1 act (writes X1[wb].h2) ========
        #pragma unroll
        for (int mi = 0; mi < 2; ++mi) { acc[mi][0] = (float4v){0,0,0,0}; acc[mi][1] = (float4v){0,0,0,0}; }
        {
            const short* X1h2 = X1 + rb * X1BUF;
            const int kt3sel = (q == 0) ? 0 : rb * X1BUF;   // kt3: kq0 = h1 (buf0), kq1-3 = h2 (rb)
            #pragma unroll
            for (int kt = 0; kt < 7; ++kt) {
                const short* base = (kt < 3) ? X1 : ((kt == 3) ? (X1 + kt3sel) : X1h2);
                const short8v b0 = *(const short8v*)(base + (((size_t)kt * 2 + 0) * 64 + lane) * 8);
                const short8v b1 = *(const short8v*)(base + (((size_t)kt * 2 + 1) * 64 + lane) * 8);
                #pragma unroll
                for (int mi = 0; mi < 2; ++mi) {
                    if (mi < nmt) {
                        acc[mi][0] = __builtin_amdgcn_mfma_f32_16x16x32_bf16(wreg[mi][kt], b0, acc[mi][0], 0, 0, 0);
                        acc[mi][1] = __builtin_amdgcn_mfma_f32_16x16x32_bf16(wreg[mi][kt], b1, acc[mi][1], 0, 0, 0);
                    }
                }
            }
        }
        const float wet = wend[t];
        #pragma unroll
        for (int mi = 0; mi < 2; ++mi) {
            if (mi < nmt) {
                const int cell = (mt0 + mi) * 4 + q;
                #pragma unroll
                for (int nh = 0; nh < 2; ++nh) {
                    const float iv = sigm_(acc[mi][nh][0]);
                    const float fv = sigm_(acc[mi][nh][1]);
                    const float gv = tanh_(acc[mi][nh][2]);
                    const float ov = sigm_(acc[mi][nh][3]);
                    const float c  = fv * c2[mi][nh] + iv * gv;
                    c2[mi][nh] = c;
                    const float h = ov * tanh_(c);
                    macc[mi][nh] = fmaf(wet, h, macc[mi][nh]);
                    if (!fin) X1[wb * X1BUF + aX1h2[mi][nh]] = f2bf(h);   // h2(t) -> write buf
                    if (fin) {
                        const int b = bh * 32 + nh * 16 + cl;
                        out[8064 + ((size_t)(n * 2 + 1) * 64 + b) * HH + cell] = h;
                        out[8064 + 1612800 + ((size_t)(n * 2 + 1) * 64 + b) * HH + cell] = c;
                    }
                }
            }
        }
        // write x(t+1) into X0[wb] kt0, nh = w (k0..17 only; h1(t) already at k>=18 of wb)
        if (doX) {
            short* X0w = X0 + wb * X0BUF;
            if (q < 2) {
                short8v pv;
                pv[0] = f2bf(xv0); pv[1] = f2bf(xv1); pv[2] = f2bf(xv2); pv[3] = f2bf(xv3);
                pv[4] = f2bf(xv4); pv[5] = f2bf(xv5); pv[6] = f2bf(xv6); pv[7] = f2bf(xv7);
                *(short8v*)(X0w + ((size_t)w * 64 + lane) * 8) = pv;       // nh = w
            } else if (q == 2) {
                const unsigned lo = (unsigned short)f2bf(xv0);
                *(unsigned*)(X0w + ((size_t)w * 64 + lane) * 8) = (0x3F80u << 16) | lo;
            }
        }
        __syncthreads();   // BARRIER 2: h2(t) / x(t+1) visible
    }

    // -------- epilogue: out[b,0,n,0] (red overlays Al) --------
    #pragma unroll
    for (int mi = 0; mi < 2; ++mi) {
        if (mi < nmt) {
            const int cell = (mt0 + mi) * 4 + q;
            #pragma unroll
            for (int nh = 0; nh < 2; ++nh)
                red[cell * 32 + nh * 16 + cl] = wlin[cell] * macc[mi][nh];
        }
    }
    __syncthreads();
    if (tid < 32) {
        float s = 0.0f;
        for (int j = 0; j < HH; ++j) s += red[j * 32 + tid];
        float ws = 0.0f;
        for (int t2 = 0; t2 < TT; ++t2) ws += wend[t2];
        s += blin[0] * ws + bend[0];
        out[(size_t)(bh * 32 + tid) * NN + n] = s;
    }
}

extern "C" void kernel_launch(void* const* d_in, const int* in_sizes, int n_in,
                              void* d_out, int out_size, void* d_ws, size_t ws_size,
                              hipStream_t stream) {
    const float* x    = (const float*)d_in[0];
    const float* Wih0 = (const float*)d_in[1];
    const float* Whh0 = (const float*)d_in[2];
    const float* bih0 = (const float*)d_in[3];
    const float* bhh0 = (const float*)d_in[4];
    const float* Wih1 = (const float*)d_in[5];
    const float* Whh1 = (const float*)d_in[6];
    const float* bih1 = (const float*)d_in[7];
    const float* bhh1 = (const float*)d_in[8];
    const float* wlin = (const float*)d_in[9];
    const float* blin = (const float*)d_in[10];
    const float* wend = (const float*)d_in[11];
    const float* bend = (const float*)d_in[12];
    (void)d_ws; (void)ws_size; (void)in_sizes; (void)n_in; (void)out_size;

    lstm_one<<<dim3(NN * 2), dim3(1024), LDS_BYTES, stream>>>(
        x, Wih0, Whh0, bih0, bhh0, Wih1, Whh1, bih1, bhh1,
        wlin, blin, wend, bend, (float*)d_out);
}